// Round 11
// baseline (96.501 us; speedup 1.0000x reference)
//
#include <hip/hip_runtime.h>
#include <hip/hip_fp16.h>

typedef _Float16 half8 __attribute__((ext_vector_type(8)));
typedef float f32x4 __attribute__((ext_vector_type(4)));

#define B_   8192
#define DIN  2048
#define C_   1000
#define CP   1024
#define NP2  512   // u,v interleaved rows

// ---- workspace layout (bytes) ----
static const size_t OFF_XH  = 0;                                   // xh  [8192][2048] f16
static const size_t OFF_WH  = OFF_XH  + (size_t)B_ * DIN * 2;      // wh  [1024][2048] f16 (rows>=1000 zero)
static const size_t OFF_UVH = OFF_WH  + (size_t)CP * DIN * 2;      // uvh [512][1024]  f16
static const size_t OFF_PH  = OFF_UVH + (size_t)NP2 * CP * 2;      // predsh [8192][1024] f16
static const size_t OFF_SC  = OFF_PH  + (size_t)B_ * CP * 2;       // scores [8192] f32
static const size_t OFF_RS  = OFF_SC  + (size_t)B_ * 4;            // rowsum [8192] f32
static const size_t OFF_CNT = OFF_RS  + (size_t)B_ * 4;            // done-counter (int, 16B slot)
static const size_t WS_NEED = OFF_CNT + 16;

#define FENCE asm volatile("" ::: "memory")
#define BARRIER do { FENCE; __builtin_amdgcn_s_barrier(); FENCE; } while (0)

__device__ __forceinline__ void gload16(const void* g, void* l) {
  __builtin_amdgcn_global_load_lds(
      (const __attribute__((address_space(1))) void*)g,
      (__attribute__((address_space(3))) void*)l, 16, 0, 0);
}

// ---------------- prep: f32 -> f16 conversions + zeroing ----------------
// x-section: 16 elems/thread (4x dwordx4 loads, 2x 16B stores).
__global__ __launch_bounds__(256) void prep_kernel(
    const float* __restrict__ x, const float* __restrict__ Wm,
    const float* __restrict__ u, const float* __restrict__ v,
    _Float16* __restrict__ xh, _Float16* __restrict__ wh,
    _Float16* __restrict__ uvh, float* __restrict__ scores,
    float* __restrict__ rowsum, int* __restrict__ cnt)
{
  const long NX  = (long)B_ * DIN / 16;     // 1,048,576 groups of 16
  const long NW  = (long)CP * DIN / 8;      //   262,144 groups of 8
  const long NUV = (long)NP2 * CP / 8;      //    65,536
  const long NZ  = 2 * (long)B_ / 8;        //     2,048
  const long T   = NX + NW + NUV + NZ;
  if (blockIdx.x == 0 && threadIdx.x == 0) *cnt = 0;
  for (long idx = (long)blockIdx.x * blockDim.x + threadIdx.x; idx < T;
       idx += (long)gridDim.x * blockDim.x) {
    if (idx < NX) {
      long e = idx * 16;
      float4 p0 = *(const float4*)(x + e);
      float4 p1 = *(const float4*)(x + e + 4);
      float4 p2 = *(const float4*)(x + e + 8);
      float4 p3 = *(const float4*)(x + e + 12);
      half8 h0, h1;
      h0[0] = (_Float16)p0.x; h0[1] = (_Float16)p0.y; h0[2] = (_Float16)p0.z; h0[3] = (_Float16)p0.w;
      h0[4] = (_Float16)p1.x; h0[5] = (_Float16)p1.y; h0[6] = (_Float16)p1.z; h0[7] = (_Float16)p1.w;
      h1[0] = (_Float16)p2.x; h1[1] = (_Float16)p2.y; h1[2] = (_Float16)p2.z; h1[3] = (_Float16)p2.w;
      h1[4] = (_Float16)p3.x; h1[5] = (_Float16)p3.y; h1[6] = (_Float16)p3.z; h1[7] = (_Float16)p3.w;
      *(half8*)(xh + e)     = h0;
      *(half8*)(xh + e + 8) = h1;
    } else if (idx < NX + NW) {
      long e = (idx - NX) * 8;
      int row = (int)(e >> 11);
      half8 h;
      if (row < C_) {
        float4 p0 = *(const float4*)(Wm + e);
        float4 p1 = *(const float4*)(Wm + e + 4);
        h[0] = (_Float16)p0.x; h[1] = (_Float16)p0.y; h[2] = (_Float16)p0.z; h[3] = (_Float16)p0.w;
        h[4] = (_Float16)p1.x; h[5] = (_Float16)p1.y; h[6] = (_Float16)p1.z; h[7] = (_Float16)p1.w;
      } else {
        h = (half8)(_Float16)0.f;
      }
      *(half8*)(wh + e) = h;
    } else if (idx < NX + NW + NUV) {
      long e = (idx - NX - NW) * 8;
      int j = (int)(e >> 10);
      int k = (int)(e & 1023);
      const float* src = (j & 1) ? v : u;
      int p = j >> 1;
      half8 h;
      #pragma unroll
      for (int t = 0; t < 8; ++t) {
        int kk = k + t;
        h[t] = (kk < C_) ? (_Float16)src[(size_t)p * C_ + kk] : (_Float16)0.f;
      }
      *(half8*)(uvh + e) = h;
    } else {
      long e = (idx - NX - NW - NUV) * 8;
      float4 z = {0.f, 0.f, 0.f, 0.f};
      if (e < B_) {
        *(float4*)(scores + e) = z; *(float4*)(scores + e + 4) = z;
      } else {
        long r = e - B_;
        *(float4*)(rowsum + r) = z; *(float4*)(rowsum + r + 4) = z;
      }
    }
  }
}

// ---------------- main GEMM: preds = xh @ wh^T + bm (r5-validated, 45.5us) ----------------
// 256x128 tile, BK=64, 512 threads = 8 waves (4M x 2N), wave tile 64x64.
// 3-buffer LDS (3 x 48KB). 4 phases per K-tile, each phase:
//   {4 ds_read_b128 (for NEXT phase's MFMA) || 1-2 global_load_lds -> barrier
//    -> setprio(1) 8 MFMA setprio(0)}.
// Fragment register reuse: P0 reads A-high(t), P1 reads B-high(t),
// P2 reads A-low(t+1), P3 reads B-low(t+1). vmcnt(4) once per K-tile.
__global__ __launch_bounds__(512) void gemm1_kernel(
    const _Float16* __restrict__ xh, const _Float16* __restrict__ wh,
    const float* __restrict__ bmv, float* __restrict__ preds,
    _Float16* __restrict__ predsh, float* __restrict__ rowsum)
{
  // per buffer: A[256][64] f16 (32KB) @ +0, B[128][64] f16 (16KB) @ +32768
  __shared__ _Float16 lds[3 * 24576];   // 144 KB
  const int tid  = threadIdx.x;
  const int lane = tid & 63;
  const int w    = tid >> 6;       // 0..7
  const int wm   = w >> 1;         // 0..3 (M quarter, 64 rows)
  const int wn   = w & 1;          // 0..1 (N half, 64 cols)
  const int bm0  = blockIdx.x * 256;
  const int bn0  = blockIdx.y * 128;

  f32x4 acc[4][4] = {};

  const _Float16* srcA[4];
  const _Float16* srcB[2];
  #pragma unroll
  for (int k = 0; k < 4; ++k) {
    int slot = k * 512 + tid;
    int row  = slot >> 3;              // 0..255
    int cb   = (slot & 7) << 4;
    int scb  = cb ^ ((row & 7) << 4);
    srcA[k] = xh + (size_t)(bm0 + row) * DIN + (scb >> 1);
  }
  #pragma unroll
  for (int k = 0; k < 2; ++k) {
    int slot = k * 512 + tid;
    int row  = slot >> 3;              // 0..127
    int cb   = (slot & 7) << 4;
    int scb  = cb ^ ((row & 7) << 4);
    srcB[k] = wh + (size_t)(bn0 + row) * DIN + (scb >> 1);
  }

  int aoff[4][2], boff[4][2];
  #pragma unroll
  for (int m = 0; m < 4; ++m) {
    #pragma unroll
    for (int ks = 0; ks < 2; ++ks) {
      int ra = wm * 64 + m * 16 + (lane & 15);
      int kb = ks * 64 + (lane >> 4) * 16;
      aoff[m][ks] = ra * 128 + (kb ^ ((ra & 7) << 4));
    }
  }
  #pragma unroll
  for (int n = 0; n < 4; ++n) {
    #pragma unroll
    for (int ks = 0; ks < 2; ++ks) {
      int rb = wn * 64 + n * 16 + (lane & 15);
      int kb = ks * 64 + (lane >> 4) * 16;
      boff[n][ks] = 32768 + rb * 128 + (kb ^ ((rb & 7) << 4));
    }
  }

  half8 aLa[2][2], aLb[2][2], aHf[2][2], bLf[2][2], bHf[2][2];

  auto stA = [&](int cs, int k) {
    gload16(srcA[k], (char*)lds + cs * 49152 + k * 8192 + w * 1024);
  };
  auto stB = [&](int cs, int k) {
    gload16(srcB[k], (char*)lds + cs * 49152 + 32768 + k * 8192 + w * 1024);
  };
  auto advance = [&]() {
    #pragma unroll
    for (int k = 0; k < 4; ++k) srcA[k] += 64;
    srcB[0] += 64; srcB[1] += 64;
  };
  auto rdAH = [&](const char* b) {
    #pragma unroll
    for (int m = 0; m < 2; ++m)
      #pragma unroll
      for (int ks = 0; ks < 2; ++ks)
        aHf[m][ks] = *(const half8*)(b + aoff[m + 2][ks]);
  };
  auto rdBH = [&](const char* b) {
    #pragma unroll
    for (int n = 0; n < 2; ++n)
      #pragma unroll
      for (int ks = 0; ks < 2; ++ks)
        bHf[n][ks] = *(const half8*)(b + boff[n + 2][ks]);
  };
  auto rdAL = [&](const char* b, half8 (&d)[2][2]) {
    #pragma unroll
    for (int m = 0; m < 2; ++m)
      #pragma unroll
      for (int ks = 0; ks < 2; ++ks)
        d[m][ks] = *(const half8*)(b + aoff[m][ks]);
  };
  auto rdBL = [&](const char* b) {
    #pragma unroll
    for (int n = 0; n < 2; ++n)
      #pragma unroll
      for (int ks = 0; ks < 2; ++ks)
        bLf[n][ks] = *(const half8*)(b + boff[n][ks]);
  };
  auto mfLL = [&](half8 (&aL)[2][2]) {
    #pragma unroll
    for (int m = 0; m < 2; ++m)
      #pragma unroll
      for (int n = 0; n < 2; ++n)
        #pragma unroll
        for (int ks = 0; ks < 2; ++ks)
          acc[m][n] = __builtin_amdgcn_mfma_f32_16x16x32_f16(aL[m][ks], bLf[n][ks], acc[m][n], 0, 0, 0);
  };
  auto mfHL = [&]() {
    #pragma unroll
    for (int m = 0; m < 2; ++m)
      #pragma unroll
      for (int n = 0; n < 2; ++n)
        #pragma unroll
        for (int ks = 0; ks < 2; ++ks)
          acc[m + 2][n] = __builtin_amdgcn_mfma_f32_16x16x32_f16(aHf[m][ks], bLf[n][ks], acc[m + 2][n], 0, 0, 0);
  };
  auto mfLH = [&](half8 (&aL)[2][2]) {
    #pragma unroll
    for (int m = 0; m < 2; ++m)
      #pragma unroll
      for (int n = 0; n < 2; ++n)
        #pragma unroll
        for (int ks = 0; ks < 2; ++ks)
          acc[m][n + 2] = __builtin_amdgcn_mfma_f32_16x16x32_f16(aL[m][ks], bHf[n][ks], acc[m][n + 2], 0, 0, 0);
  };
  auto mfHH = [&]() {
    #pragma unroll
    for (int m = 0; m < 2; ++m)
      #pragma unroll
      for (int n = 0; n < 2; ++n)
        #pragma unroll
        for (int ks = 0; ks < 2; ++ks)
          acc[m + 2][n + 2] = __builtin_amdgcn_mfma_f32_16x16x32_f16(aHf[m][ks], bHf[n][ks], acc[m + 2][n + 2], 0, 0, 0);
  };

  // ---- prologue: stage tile0 -> buf0, tile1 -> buf1 ----
  #pragma unroll
  for (int k = 0; k < 4; ++k) stA(0, k);
  stB(0, 0); stB(0, 1);
  advance();
  #pragma unroll
  for (int k = 0; k < 4; ++k) stA(1, k);
  stB(1, 0); stB(1, 1);
  advance();
  asm volatile("s_waitcnt vmcnt(6)" ::: "memory");   // tile0 resident
  BARRIER;
  rdAL((const char*)lds, aLa);
  rdBL((const char*)lds);

  // ---- main loop: tiles 0..29, two per iteration ----
  int c0 = 0;
  #pragma unroll 1
  for (int t = 0; t < 30; t += 2) {
    const int c1 = (c0 == 2) ? 0 : c0 + 1;
    const int c2 = (c1 == 2) ? 0 : c1 + 1;
    const char* bt  = (const char*)lds + c0 * 49152;
    const char* bn1 = (const char*)lds + c1 * 49152;
    const char* bn2 = (const char*)lds + c2 * 49152;

    // ===== even tile t (current A-low = aLa) =====
    rdAH(bt);  stA(c2, 0); stA(c2, 1);                 // P0
    BARRIER;
    __builtin_amdgcn_s_setprio(1); mfLL(aLa); __builtin_amdgcn_s_setprio(0);

    rdBH(bt);  stA(c2, 2); stA(c2, 3);                 // P1
    asm volatile("s_waitcnt vmcnt(4)" ::: "memory");   // tile t+1 resident
    BARRIER;
    __builtin_amdgcn_s_setprio(1); mfHL(); __builtin_amdgcn_s_setprio(0);

    rdAL(bn1, aLb);  stB(c2, 0);                       // P2 (prefetch t+1 A-low)
    BARRIER;
    __builtin_amdgcn_s_setprio(1); mfLH(aLa); __builtin_amdgcn_s_setprio(0);

    rdBL(bn1);  stB(c2, 1); advance();                 // P3 (prefetch t+1 B-low)
    BARRIER;
    __builtin_amdgcn_s_setprio(1); mfHH(); __builtin_amdgcn_s_setprio(0);

    // ===== odd tile t+1 (current A-low = aLb) =====
    rdAH(bn1);  stA(c0, 0); stA(c0, 1);                // stage tile t+3 -> buf c0
    BARRIER;
    __builtin_amdgcn_s_setprio(1); mfLL(aLb); __builtin_amdgcn_s_setprio(0);

    rdBH(bn1);  stA(c0, 2); stA(c0, 3);
    asm volatile("s_waitcnt vmcnt(4)" ::: "memory");   // tile t+2 resident
    BARRIER;
    __builtin_amdgcn_s_setprio(1); mfHL(); __builtin_amdgcn_s_setprio(0);

    rdAL(bn2, aLa);  stB(c0, 0);                       // prefetch t+2 A-low
    BARRIER;
    __builtin_amdgcn_s_setprio(1); mfLH(aLb); __builtin_amdgcn_s_setprio(0);

    rdBL(bn2);  stB(c0, 1); advance();                 // prefetch t+2 B-low
    BARRIER;
    __builtin_amdgcn_s_setprio(1); mfHH(); __builtin_amdgcn_s_setprio(0);

    c0 = c2;
  }

  // ---- tail: tile 30 (buf0, cur aLa; prefetch tile31 from buf1) ----
  {
    const char* bt  = (const char*)lds;
    const char* bn1 = (const char*)lds + 49152;
    rdAH(bt);
    BARRIER;
    __builtin_amdgcn_s_setprio(1); mfLL(aLa); __builtin_amdgcn_s_setprio(0);
    rdBH(bt);
    asm volatile("s_waitcnt vmcnt(0)" ::: "memory");   // tile31 resident
    BARRIER;
    __builtin_amdgcn_s_setprio(1); mfHL(); __builtin_amdgcn_s_setprio(0);
    rdAL(bn1, aLb);
    BARRIER;
    __builtin_amdgcn_s_setprio(1); mfLH(aLa); __builtin_amdgcn_s_setprio(0);
    rdBL(bn1);
    BARRIER;
    __builtin_amdgcn_s_setprio(1); mfHH(); __builtin_amdgcn_s_setprio(0);
    // ---- tile 31 (buf1, cur aLb): no barriers needed ----
    rdAH(bn1); rdBH(bn1);
    mfLL(aLb); mfHL(); mfLH(aLb); mfHH();
  }

  // ---- epilogue: bias add, f32 preds, f16 predsh, rowsum partials ----
  float rp[4][4] = {};
  #pragma unroll
  for (int m = 0; m < 4; ++m) {
    #pragma unroll
    for (int n = 0; n < 4; ++n) {
      f32x4 d = acc[m][n];
      int gc = bn0 + wn * 64 + n * 16 + (lane & 15);
      float bias = (gc < C_) ? bmv[gc] : 0.f;
      #pragma unroll
      for (int j = 0; j < 4; ++j) {
        int gr = bm0 + wm * 64 + m * 16 + (lane >> 4) * 4 + j;
        float val = d[j] + bias;
        predsh[(size_t)gr * CP + gc] = (_Float16)val;
        if (gc < C_) preds[(size_t)gr * C_ + gc] = val;
        rp[m][j] += val;
      }
    }
  }
  #pragma unroll
  for (int m = 0; m < 4; ++m) {
    #pragma unroll
    for (int j = 0; j < 4; ++j) {
      float s = rp[m][j];
      s += __shfl_xor(s, 1); s += __shfl_xor(s, 2);
      s += __shfl_xor(s, 4); s += __shfl_xor(s, 8);
      if ((lane & 15) == 0) {
        int gr = bm0 + wm * 64 + m * 16 + (lane >> 4) * 4 + j;
        atomicAdd(&rowsum[gr], s);
      }
    }
  }
}

// ---------------- gating GEMM + fused final (last-block softmax total) ----------------
__global__ __launch_bounds__(256) void gemm2_kernel(
    const _Float16* __restrict__ predsh, const _Float16* __restrict__ uvh,
    const float* __restrict__ wv, float* __restrict__ scores,
    const float* __restrict__ rowsum, float* __restrict__ out,
    int* __restrict__ cnt)
{
  __shared__ _Float16 sA[2][64 * 64];
  __shared__ _Float16 sB[2][128 * 64];
  const int tid  = threadIdx.x;
  const int lane = tid & 63;
  const int w    = tid >> 6;
  const int wm   = w >> 1, wn = w & 1;   // wave owns 32x64
  const int bm0  = blockIdx.x * 64;
  const int bn0  = blockIdx.y * 128;

  f32x4 acc[2][4] = {};

  const _Float16* srcA[2]; const _Float16* srcB[4];
  #pragma unroll
  for (int i = 0; i < 2; ++i) {
    int slot = i * 256 + tid;
    int row  = slot >> 3;
    int cb   = (slot & 7) << 4;
    int scb  = cb ^ ((row & 7) << 4);
    srcA[i] = predsh + (size_t)(bm0 + row) * CP + (scb >> 1);
  }
  #pragma unroll
  for (int i = 0; i < 4; ++i) {
    int slot = i * 256 + tid;
    int row  = slot >> 3;
    int cb   = (slot & 7) << 4;
    int scb  = cb ^ ((row & 7) << 4);
    srcB[i] = uvh + (size_t)(bn0 + row) * CP + (scb >> 1);
  }
  int aoff[2][2], boff[4][2];
  #pragma unroll
  for (int ks = 0; ks < 2; ++ks) {
    int kb = ks * 64 + (lane >> 4) * 16;
    #pragma unroll
    for (int mi = 0; mi < 2; ++mi) {
      int ra = wm * 32 + mi * 16 + (lane & 15);
      aoff[mi][ks] = ra * 128 + (kb ^ ((ra & 7) << 4));
    }
    #pragma unroll
    for (int ni = 0; ni < 4; ++ni) {
      int rb = wn * 64 + ni * 16 + (lane & 15);
      boff[ni][ks] = rb * 128 + (kb ^ ((rb & 7) << 4));
    }
  }

  auto stage = [&](int c) {
    #pragma unroll
    for (int i = 0; i < 2; ++i) {
      gload16(srcA[i], &sA[c][(i * 4 + w) * 512]);
      srcA[i] += 64;
    }
    #pragma unroll
    for (int i = 0; i < 4; ++i) {
      gload16(srcB[i], &sB[c][(i * 4 + w) * 512]);
      srcB[i] += 64;
    }
  };

  auto compute = [&](int c) {
    const char* bA = (const char*)&sA[c][0];
    const char* bB = (const char*)&sB[c][0];
    #pragma unroll
    for (int ks = 0; ks < 2; ++ks) {
      half8 a[2], b[4];
      #pragma unroll
      for (int mi = 0; mi < 2; ++mi) a[mi] = *(const half8*)(bA + aoff[mi][ks]);
      #pragma unroll
      for (int ni = 0; ni < 4; ++ni) b[ni] = *(const half8*)(bB + boff[ni][ks]);
      #pragma unroll
      for (int mi = 0; mi < 2; ++mi)
        #pragma unroll
        for (int ni = 0; ni < 4; ++ni)
          acc[mi][ni] = __builtin_amdgcn_mfma_f32_16x16x32_f16(a[mi], b[ni], acc[mi][ni], 0, 0, 0);
    }
  };

  const int NT = CP / 64;   // 16
  stage(0);
  #pragma unroll 1
  for (int kt = 0; kt < NT; kt += 2) {
    stage(1);
    asm volatile("s_waitcnt vmcnt(6)" ::: "memory");
    BARRIER;
    compute(0);
    BARRIER;
    if (kt + 2 < NT) {
      stage(0);
      asm volatile("s_waitcnt vmcnt(6)" ::: "memory");
    } else {
      asm volatile("s_waitcnt vmcnt(0)" ::: "memory");
    }
    BARRIER;
    compute(1);
    BARRIER;
  }

  float sp[2][4] = {};
  #pragma unroll
  for (int mi = 0; mi < 2; ++mi) {
    #pragma unroll
    for (int ni = 0; ni < 4; ++ni) {
      f32x4 d = acc[mi][ni];
      int gc = bn0 + wn * 64 + ni * 16 + (lane & 15);   // even=u col, odd=v col
      float wq = wv[gc >> 1];
      bool even = ((gc & 1) == 0);
      #pragma unroll
      for (int j = 0; j < 4; ++j) {
        float t  = d[j];
        float pr = __shfl_xor(t, 1);
        float th = 2.f / (1.f + __expf(-2.f * t)) - 1.f;
        float sg = 1.f / (1.f + __expf(-pr));
        sp[mi][j] += even ? (th * sg * wq) : 0.f;
      }
    }
  }
  #pragma unroll
  for (int mi = 0; mi < 2; ++mi) {
    #pragma unroll
    for (int j = 0; j < 4; ++j) {
      float s = sp[mi][j];
      s += __shfl_xor(s, 1); s += __shfl_xor(s, 2);
      s += __shfl_xor(s, 4); s += __shfl_xor(s, 8);
      if ((lane & 15) == 0) {
        int gr = bm0 + wm * 32 + mi * 16 + (lane >> 4) * 4 + j;
        atomicAdd(&scores[gr], s);
      }
    }
  }

  // ---- fused final: last block computes softmax-weighted total ----
  __syncthreads();                    // all this block's score atomics issued
  __shared__ int lastFlag;
  if (tid == 0) {
    __threadfence();                  // release: scores atomics before counter
    int done = atomicAdd(cnt, 1);
    lastFlag = (done == (int)(gridDim.x * gridDim.y) - 1);
  }
  __syncthreads();
  if (lastFlag) {
    __threadfence();                  // acquire
    __shared__ float redm[4], redse[4], redsr[4];
    const int wid = tid >> 6;
    // pass 1: global max (agent-scope atomic loads: cross-XCD coherent)
    float m = -3.4e38f;
    #pragma unroll
    for (int i = 0; i < 32; ++i) {
      float sc = __hip_atomic_load(&scores[tid + i * 256], __ATOMIC_RELAXED,
                                   __HIP_MEMORY_SCOPE_AGENT);
      m = fmaxf(m, sc);
    }
    #pragma unroll
    for (int off = 1; off < 64; off <<= 1) m = fmaxf(m, __shfl_xor(m, off));
    if (lane == 0) redm[wid] = m;
    __syncthreads();
    m = fmaxf(fmaxf(redm[0], redm[1]), fmaxf(redm[2], redm[3]));
    // pass 2: exp-sum and weighted rowsum
    float se = 0.f, sr = 0.f;
    #pragma unroll
    for (int i = 0; i < 32; ++i) {
      float sc = __hip_atomic_load(&scores[tid + i * 256], __ATOMIC_RELAXED,
                                   __HIP_MEMORY_SCOPE_AGENT);
      float rs = __hip_atomic_load(&rowsum[tid + i * 256], __ATOMIC_RELAXED,
                                   __HIP_MEMORY_SCOPE_AGENT);
      float e = __expf(sc - m);
      se += e;
      sr += e * rs;
    }
    #pragma unroll
    for (int off = 1; off < 64; off <<= 1) { se += __shfl_xor(se, off); sr += __shfl_xor(sr, off); }
    if (lane == 0) { redse[wid] = se; redsr[wid] = sr; }
    __syncthreads();
    if (tid == 0) {
      float tse = redse[0] + redse[1] + redse[2] + redse[3];
      float tsr = redsr[0] + redsr[1] + redsr[2] + redsr[3];
      out[(size_t)B_ * C_] = tsr / tse;
    }
  }
}

extern "C" void kernel_launch(void* const* d_in, const int* in_sizes, int n_in,
                              void* d_out, int out_size, void* d_ws, size_t ws_size,
                              hipStream_t stream)
{
  const float* x   = (const float*)d_in[0];
  const float* Wm  = (const float*)d_in[1];
  const float* bmv = (const float*)d_in[2];
  const float* u   = (const float*)d_in[3];
  const float* v   = (const float*)d_in[4];
  const float* wv  = (const float*)d_in[5];
  float* out = (float*)d_out;

  if (ws_size < WS_NEED) return;

  char* ws = (char*)d_ws;
  _Float16* xh     = (_Float16*)(ws + OFF_XH);
  _Float16* wh     = (_Float16*)(ws + OFF_WH);
  _Float16* uvh    = (_Float16*)(ws + OFF_UVH);
  _Float16* predsh = (_Float16*)(ws + OFF_PH);
  float*    scores = (float*)(ws + OFF_SC);
  float*    rowsum = (float*)(ws + OFF_RS);
  int*      cnt    = (int*)(ws + OFF_CNT);

  prep_kernel<<<2048, 256, 0, stream>>>(x, Wm, u, v, xh, wh, uvh, scores, rowsum, cnt);
  gemm1_kernel<<<dim3(32, 8), 512, 0, stream>>>(xh, wh, bmv, out, predsh, rowsum);
  gemm2_kernel<<<dim3(128, 4), 256, 0, stream>>>(predsh, uvh, wv, scores, rowsum, out, cnt);
}

// Round 12
// 92.482 us; speedup vs baseline: 1.0435x; 1.0435x over previous
//
#include <hip/hip_runtime.h>
#include <hip/hip_fp16.h>

typedef _Float16 half8 __attribute__((ext_vector_type(8)));
typedef float f32x4 __attribute__((ext_vector_type(4)));

#define B_   8192
#define DIN  2048
#define C_   1000
#define CP   1024
#define NP2  512   // u,v interleaved rows

// ---- workspace layout (bytes) ----
static const size_t OFF_XH  = 0;                                   // xh  [8192][2048] f16
static const size_t OFF_WH  = OFF_XH  + (size_t)B_ * DIN * 2;      // wh  [1024][2048] f16 (rows>=1000 zero)
static const size_t OFF_UVH = OFF_WH  + (size_t)CP * DIN * 2;      // uvh [512][1024]  f16
static const size_t OFF_PH  = OFF_UVH + (size_t)NP2 * CP * 2;      // predsh [8192][1024] f16
static const size_t OFF_SC  = OFF_PH  + (size_t)B_ * CP * 2;       // scores [8192] f32
static const size_t OFF_RS  = OFF_SC  + (size_t)B_ * 4;            // rowsum [8192] f32
static const size_t WS_NEED = OFF_RS  + (size_t)B_ * 4;

#define FENCE asm volatile("" ::: "memory")
#define BARRIER do { FENCE; __builtin_amdgcn_s_barrier(); FENCE; } while (0)

__device__ __forceinline__ void gload16(const void* g, void* l) {
  __builtin_amdgcn_global_load_lds(
      (const __attribute__((address_space(1))) void*)g,
      (__attribute__((address_space(3))) void*)l, 16, 0, 0);
}

// ---------------- prep_x: dedicated branch-free x(f32) -> xh(f16) ----------------
// 524,288 threads, each converts 4 groups of 8 floats at 4MB stride.
// All 8 dwordx4 loads issued before any cvt/store (max MLP); zero loop/branch.
__global__ __launch_bounds__(256) void prep_x_kernel(
    const float* __restrict__ x, _Float16* __restrict__ xh)
{
  const long g = (long)blockIdx.x * 256 + threadIdx.x;   // 0..524287
  const long STRIDE = 524288L * 8;                        // floats between groups
  long e0 = g * 8;
  float4 p[4][2];
  #pragma unroll
  for (int j = 0; j < 4; ++j) {
    p[j][0] = *(const float4*)(x + e0 + j * STRIDE);
    p[j][1] = *(const float4*)(x + e0 + j * STRIDE + 4);
  }
  #pragma unroll
  for (int j = 0; j < 4; ++j) {
    half8 h;
    h[0] = (_Float16)p[j][0].x; h[1] = (_Float16)p[j][0].y;
    h[2] = (_Float16)p[j][0].z; h[3] = (_Float16)p[j][0].w;
    h[4] = (_Float16)p[j][1].x; h[5] = (_Float16)p[j][1].y;
    h[6] = (_Float16)p[j][1].z; h[7] = (_Float16)p[j][1].w;
    *(half8*)(xh + e0 + j * STRIDE) = h;
  }
}

// ---------------- prep_rest: Wm/uv conversions + zeroing (r3-validated) ----------------
__global__ __launch_bounds__(256) void prep_rest_kernel(
    const float* __restrict__ Wm,
    const float* __restrict__ u, const float* __restrict__ v,
    _Float16* __restrict__ wh, _Float16* __restrict__ uvh,
    float* __restrict__ scores, float* __restrict__ rowsum)
{
  const long NW  = (long)CP * DIN / 8;      //   262,144
  const long NUV = (long)NP2 * CP / 8;      //    65,536
  const long NZ  = 2 * (long)B_ / 8;        //     2,048
  const long T   = NW + NUV + NZ;           //   329,728 = 1288*256 exactly
  for (long idx = (long)blockIdx.x * blockDim.x + threadIdx.x; idx < T;
       idx += (long)gridDim.x * blockDim.x) {
    if (idx < NW) {
      long e = idx * 8;
      int row = (int)(e >> 11);
      half8 h;
      if (row < C_) {
        float4 p0 = *(const float4*)(Wm + e);
        float4 p1 = *(const float4*)(Wm + e + 4);
        h[0] = (_Float16)p0.x; h[1] = (_Float16)p0.y; h[2] = (_Float16)p0.z; h[3] = (_Float16)p0.w;
        h[4] = (_Float16)p1.x; h[5] = (_Float16)p1.y; h[6] = (_Float16)p1.z; h[7] = (_Float16)p1.w;
      } else {
        h = (half8)(_Float16)0.f;
      }
      *(half8*)(wh + e) = h;
    } else if (idx < NW + NUV) {
      long e = (idx - NW) * 8;
      int j = (int)(e >> 10);
      int k = (int)(e & 1023);
      const float* src = (j & 1) ? v : u;
      int p = j >> 1;
      half8 h;
      #pragma unroll
      for (int t = 0; t < 8; ++t) {
        int kk = k + t;
        h[t] = (kk < C_) ? (_Float16)src[(size_t)p * C_ + kk] : (_Float16)0.f;
      }
      *(half8*)(uvh + e) = h;
    } else {
      long e = (idx - NW - NUV) * 8;
      float4 z = {0.f, 0.f, 0.f, 0.f};
      if (e < B_) {
        *(float4*)(scores + e) = z; *(float4*)(scores + e + 4) = z;
      } else {
        long r = e - B_;
        *(float4*)(rowsum + r) = z; *(float4*)(rowsum + r + 4) = z;
      }
    }
  }
}

// ---------------- main GEMM: preds = xh @ wh^T + bm (r5-validated, 45.5us) ----------------
// 256x128 tile, BK=64, 512 threads = 8 waves (4M x 2N), wave tile 64x64.
// 3-buffer LDS (3 x 48KB). 4 phases per K-tile, each phase:
//   {4 ds_read_b128 (for NEXT phase's MFMA) || 1-2 global_load_lds -> barrier
//    -> setprio(1) 8 MFMA setprio(0)}.
// Fragment register reuse: P0 reads A-high(t), P1 reads B-high(t),
// P2 reads A-low(t+1), P3 reads B-low(t+1). vmcnt(4) once per K-tile.
__global__ __launch_bounds__(512) void gemm1_kernel(
    const _Float16* __restrict__ xh, const _Float16* __restrict__ wh,
    const float* __restrict__ bmv, float* __restrict__ preds,
    _Float16* __restrict__ predsh, float* __restrict__ rowsum)
{
  // per buffer: A[256][64] f16 (32KB) @ +0, B[128][64] f16 (16KB) @ +32768
  __shared__ _Float16 lds[3 * 24576];   // 144 KB
  const int tid  = threadIdx.x;
  const int lane = tid & 63;
  const int w    = tid >> 6;       // 0..7
  const int wm   = w >> 1;         // 0..3 (M quarter, 64 rows)
  const int wn   = w & 1;          // 0..1 (N half, 64 cols)
  const int bm0  = blockIdx.x * 256;
  const int bn0  = blockIdx.y * 128;

  f32x4 acc[4][4] = {};

  const _Float16* srcA[4];
  const _Float16* srcB[2];
  #pragma unroll
  for (int k = 0; k < 4; ++k) {
    int slot = k * 512 + tid;
    int row  = slot >> 3;              // 0..255
    int cb   = (slot & 7) << 4;
    int scb  = cb ^ ((row & 7) << 4);
    srcA[k] = xh + (size_t)(bm0 + row) * DIN + (scb >> 1);
  }
  #pragma unroll
  for (int k = 0; k < 2; ++k) {
    int slot = k * 512 + tid;
    int row  = slot >> 3;              // 0..127
    int cb   = (slot & 7) << 4;
    int scb  = cb ^ ((row & 7) << 4);
    srcB[k] = wh + (size_t)(bn0 + row) * DIN + (scb >> 1);
  }

  int aoff[4][2], boff[4][2];
  #pragma unroll
  for (int m = 0; m < 4; ++m) {
    #pragma unroll
    for (int ks = 0; ks < 2; ++ks) {
      int ra = wm * 64 + m * 16 + (lane & 15);
      int kb = ks * 64 + (lane >> 4) * 16;
      aoff[m][ks] = ra * 128 + (kb ^ ((ra & 7) << 4));
    }
  }
  #pragma unroll
  for (int n = 0; n < 4; ++n) {
    #pragma unroll
    for (int ks = 0; ks < 2; ++ks) {
      int rb = wn * 64 + n * 16 + (lane & 15);
      int kb = ks * 64 + (lane >> 4) * 16;
      boff[n][ks] = 32768 + rb * 128 + (kb ^ ((rb & 7) << 4));
    }
  }

  half8 aLa[2][2], aLb[2][2], aHf[2][2], bLf[2][2], bHf[2][2];

  auto stA = [&](int cs, int k) {
    gload16(srcA[k], (char*)lds + cs * 49152 + k * 8192 + w * 1024);
  };
  auto stB = [&](int cs, int k) {
    gload16(srcB[k], (char*)lds + cs * 49152 + 32768 + k * 8192 + w * 1024);
  };
  auto advance = [&]() {
    #pragma unroll
    for (int k = 0; k < 4; ++k) srcA[k] += 64;
    srcB[0] += 64; srcB[1] += 64;
  };
  auto rdAH = [&](const char* b) {
    #pragma unroll
    for (int m = 0; m < 2; ++m)
      #pragma unroll
      for (int ks = 0; ks < 2; ++ks)
        aHf[m][ks] = *(const half8*)(b + aoff[m + 2][ks]);
  };
  auto rdBH = [&](const char* b) {
    #pragma unroll
    for (int n = 0; n < 2; ++n)
      #pragma unroll
      for (int ks = 0; ks < 2; ++ks)
        bHf[n][ks] = *(const half8*)(b + boff[n + 2][ks]);
  };
  auto rdAL = [&](const char* b, half8 (&d)[2][2]) {
    #pragma unroll
    for (int m = 0; m < 2; ++m)
      #pragma unroll
      for (int ks = 0; ks < 2; ++ks)
        d[m][ks] = *(const half8*)(b + aoff[m][ks]);
  };
  auto rdBL = [&](const char* b) {
    #pragma unroll
    for (int n = 0; n < 2; ++n)
      #pragma unroll
      for (int ks = 0; ks < 2; ++ks)
        bLf[n][ks] = *(const half8*)(b + boff[n][ks]);
  };
  auto mfLL = [&](half8 (&aL)[2][2]) {
    #pragma unroll
    for (int m = 0; m < 2; ++m)
      #pragma unroll
      for (int n = 0; n < 2; ++n)
        #pragma unroll
        for (int ks = 0; ks < 2; ++ks)
          acc[m][n] = __builtin_amdgcn_mfma_f32_16x16x32_f16(aL[m][ks], bLf[n][ks], acc[m][n], 0, 0, 0);
  };
  auto mfHL = [&]() {
    #pragma unroll
    for (int m = 0; m < 2; ++m)
      #pragma unroll
      for (int n = 0; n < 2; ++n)
        #pragma unroll
        for (int ks = 0; ks < 2; ++ks)
          acc[m + 2][n] = __builtin_amdgcn_mfma_f32_16x16x32_f16(aHf[m][ks], bLf[n][ks], acc[m + 2][n], 0, 0, 0);
  };
  auto mfLH = [&](half8 (&aL)[2][2]) {
    #pragma unroll
    for (int m = 0; m < 2; ++m)
      #pragma unroll
      for (int n = 0; n < 2; ++n)
        #pragma unroll
        for (int ks = 0; ks < 2; ++ks)
          acc[m][n + 2] = __builtin_amdgcn_mfma_f32_16x16x32_f16(aL[m][ks], bHf[n][ks], acc[m][n + 2], 0, 0, 0);
  };
  auto mfHH = [&]() {
    #pragma unroll
    for (int m = 0; m < 2; ++m)
      #pragma unroll
      for (int n = 0; n < 2; ++n)
        #pragma unroll
        for (int ks = 0; ks < 2; ++ks)
          acc[m + 2][n + 2] = __builtin_amdgcn_mfma_f32_16x16x32_f16(aHf[m][ks], bHf[n][ks], acc[m + 2][n + 2], 0, 0, 0);
  };

  // ---- prologue: stage tile0 -> buf0, tile1 -> buf1 ----
  #pragma unroll
  for (int k = 0; k < 4; ++k) stA(0, k);
  stB(0, 0); stB(0, 1);
  advance();
  #pragma unroll
  for (int k = 0; k < 4; ++k) stA(1, k);
  stB(1, 0); stB(1, 1);
  advance();
  asm volatile("s_waitcnt vmcnt(6)" ::: "memory");   // tile0 resident
  BARRIER;
  rdAL((const char*)lds, aLa);
  rdBL((const char*)lds);

  // ---- main loop: tiles 0..29, two per iteration ----
  int c0 = 0;
  #pragma unroll 1
  for (int t = 0; t < 30; t += 2) {
    const int c1 = (c0 == 2) ? 0 : c0 + 1;
    const int c2 = (c1 == 2) ? 0 : c1 + 1;
    const char* bt  = (const char*)lds + c0 * 49152;
    const char* bn1 = (const char*)lds + c1 * 49152;
    const char* bn2 = (const char*)lds + c2 * 49152;

    // ===== even tile t (current A-low = aLa) =====
    rdAH(bt);  stA(c2, 0); stA(c2, 1);                 // P0
    BARRIER;
    __builtin_amdgcn_s_setprio(1); mfLL(aLa); __builtin_amdgcn_s_setprio(0);

    rdBH(bt);  stA(c2, 2); stA(c2, 3);                 // P1
    asm volatile("s_waitcnt vmcnt(4)" ::: "memory");   // tile t+1 resident
    BARRIER;
    __builtin_amdgcn_s_setprio(1); mfHL(); __builtin_amdgcn_s_setprio(0);

    rdAL(bn1, aLb);  stB(c2, 0);                       // P2 (prefetch t+1 A-low)
    BARRIER;
    __builtin_amdgcn_s_setprio(1); mfLH(aLa); __builtin_amdgcn_s_setprio(0);

    rdBL(bn1);  stB(c2, 1); advance();                 // P3 (prefetch t+1 B-low)
    BARRIER;
    __builtin_amdgcn_s_setprio(1); mfHH(); __builtin_amdgcn_s_setprio(0);

    // ===== odd tile t+1 (current A-low = aLb) =====
    rdAH(bn1);  stA(c0, 0); stA(c0, 1);                // stage tile t+3 -> buf c0
    BARRIER;
    __builtin_amdgcn_s_setprio(1); mfLL(aLb); __builtin_amdgcn_s_setprio(0);

    rdBH(bn1);  stA(c0, 2); stA(c0, 3);
    asm volatile("s_waitcnt vmcnt(4)" ::: "memory");   // tile t+2 resident
    BARRIER;
    __builtin_amdgcn_s_setprio(1); mfHL(); __builtin_amdgcn_s_setprio(0);

    rdAL(bn2, aLa);  stB(c0, 0);                       // prefetch t+2 A-low
    BARRIER;
    __builtin_amdgcn_s_setprio(1); mfLH(aLb); __builtin_amdgcn_s_setprio(0);

    rdBL(bn2);  stB(c0, 1); advance();                 // prefetch t+2 B-low
    BARRIER;
    __builtin_amdgcn_s_setprio(1); mfHH(); __builtin_amdgcn_s_setprio(0);

    c0 = c2;
  }

  // ---- tail: tile 30 (buf0, cur aLa; prefetch tile31 from buf1) ----
  {
    const char* bt  = (const char*)lds;
    const char* bn1 = (const char*)lds + 49152;
    rdAH(bt);
    BARRIER;
    __builtin_amdgcn_s_setprio(1); mfLL(aLa); __builtin_amdgcn_s_setprio(0);
    rdBH(bt);
    asm volatile("s_waitcnt vmcnt(0)" ::: "memory");   // tile31 resident
    BARRIER;
    __builtin_amdgcn_s_setprio(1); mfHL(); __builtin_amdgcn_s_setprio(0);
    rdAL(bn1, aLb);
    BARRIER;
    __builtin_amdgcn_s_setprio(1); mfLH(aLa); __builtin_amdgcn_s_setprio(0);
    rdBL(bn1);
    BARRIER;
    __builtin_amdgcn_s_setprio(1); mfHH(); __builtin_amdgcn_s_setprio(0);
    // ---- tile 31 (buf1, cur aLb): no barriers needed ----
    rdAH(bn1); rdBH(bn1);
    mfLL(aLb); mfHL(); mfLH(aLb); mfHH();
  }

  // ---- epilogue: bias add, f32 preds, f16 predsh, rowsum partials ----
  float rp[4][4] = {};
  #pragma unroll
  for (int m = 0; m < 4; ++m) {
    #pragma unroll
    for (int n = 0; n < 4; ++n) {
      f32x4 d = acc[m][n];
      int gc = bn0 + wn * 64 + n * 16 + (lane & 15);
      float bias = (gc < C_) ? bmv[gc] : 0.f;
      #pragma unroll
      for (int j = 0; j < 4; ++j) {
        int gr = bm0 + wm * 64 + m * 16 + (lane >> 4) * 4 + j;
        float val = d[j] + bias;
        predsh[(size_t)gr * CP + gc] = (_Float16)val;
        if (gc < C_) preds[(size_t)gr * C_ + gc] = val;
        rp[m][j] += val;
      }
    }
  }
  #pragma unroll
  for (int m = 0; m < 4; ++m) {
    #pragma unroll
    for (int j = 0; j < 4; ++j) {
      float s = rp[m][j];
      s += __shfl_xor(s, 1); s += __shfl_xor(s, 2);
      s += __shfl_xor(s, 4); s += __shfl_xor(s, 8);
      if ((lane & 15) == 0) {
        int gr = bm0 + wm * 64 + m * 16 + (lane >> 4) * 4 + j;
        atomicAdd(&rowsum[gr], s);
      }
    }
  }
}

// ---------------- gating GEMM: scores partials (r5-validated) ----------------
__global__ __launch_bounds__(256) void gemm2_kernel(
    const _Float16* __restrict__ predsh, const _Float16* __restrict__ uvh,
    const float* __restrict__ wv, float* __restrict__ scores)
{
  __shared__ _Float16 sA[2][64 * 64];
  __shared__ _Float16 sB[2][128 * 64];
  const int tid  = threadIdx.x;
  const int lane = tid & 63;
  const int w    = tid >> 6;
  const int wm   = w >> 1, wn = w & 1;   // wave owns 32x64
  const int bm0  = blockIdx.x * 64;
  const int bn0  = blockIdx.y * 128;

  f32x4 acc[2][4] = {};

  const _Float16* srcA[2]; const _Float16* srcB[4];
  #pragma unroll
  for (int i = 0; i < 2; ++i) {
    int slot = i * 256 + tid;
    int row  = slot >> 3;
    int cb   = (slot & 7) << 4;
    int scb  = cb ^ ((row & 7) << 4);
    srcA[i] = predsh + (size_t)(bm0 + row) * CP + (scb >> 1);
  }
  #pragma unroll
  for (int i = 0; i < 4; ++i) {
    int slot = i * 256 + tid;
    int row  = slot >> 3;
    int cb   = (slot & 7) << 4;
    int scb  = cb ^ ((row & 7) << 4);
    srcB[i] = uvh + (size_t)(bn0 + row) * CP + (scb >> 1);
  }
  int aoff[2][2], boff[4][2];
  #pragma unroll
  for (int ks = 0; ks < 2; ++ks) {
    int kb = ks * 64 + (lane >> 4) * 16;
    #pragma unroll
    for (int mi = 0; mi < 2; ++mi) {
      int ra = wm * 32 + mi * 16 + (lane & 15);
      aoff[mi][ks] = ra * 128 + (kb ^ ((ra & 7) << 4));
    }
    #pragma unroll
    for (int ni = 0; ni < 4; ++ni) {
      int rb = wn * 64 + ni * 16 + (lane & 15);
      boff[ni][ks] = rb * 128 + (kb ^ ((rb & 7) << 4));
    }
  }

  auto stage = [&](int c) {
    #pragma unroll
    for (int i = 0; i < 2; ++i) {
      gload16(srcA[i], &sA[c][(i * 4 + w) * 512]);
      srcA[i] += 64;
    }
    #pragma unroll
    for (int i = 0; i < 4; ++i) {
      gload16(srcB[i], &sB[c][(i * 4 + w) * 512]);
      srcB[i] += 64;
    }
  };

  auto compute = [&](int c) {
    const char* bA = (const char*)&sA[c][0];
    const char* bB = (const char*)&sB[c][0];
    #pragma unroll
    for (int ks = 0; ks < 2; ++ks) {
      half8 a[2], b[4];
      #pragma unroll
      for (int mi = 0; mi < 2; ++mi) a[mi] = *(const half8*)(bA + aoff[mi][ks]);
      #pragma unroll
      for (int ni = 0; ni < 4; ++ni) b[ni] = *(const half8*)(bB + boff[ni][ks]);
      #pragma unroll
      for (int mi = 0; mi < 2; ++mi)
        #pragma unroll
        for (int ni = 0; ni < 4; ++ni)
          acc[mi][ni] = __builtin_amdgcn_mfma_f32_16x16x32_f16(a[mi], b[ni], acc[mi][ni], 0, 0, 0);
    }
  };

  const int NT = CP / 64;   // 16
  stage(0);
  #pragma unroll 1
  for (int kt = 0; kt < NT; kt += 2) {
    stage(1);
    asm volatile("s_waitcnt vmcnt(6)" ::: "memory");
    BARRIER;
    compute(0);
    BARRIER;
    if (kt + 2 < NT) {
      stage(0);
      asm volatile("s_waitcnt vmcnt(6)" ::: "memory");
    } else {
      asm volatile("s_waitcnt vmcnt(0)" ::: "memory");
    }
    BARRIER;
    compute(1);
    BARRIER;
  }

  float sp[2][4] = {};
  #pragma unroll
  for (int mi = 0; mi < 2; ++mi) {
    #pragma unroll
    for (int ni = 0; ni < 4; ++ni) {
      f32x4 d = acc[mi][ni];
      int gc = bn0 + wn * 64 + ni * 16 + (lane & 15);   // even=u col, odd=v col
      float wq = wv[gc >> 1];
      bool even = ((gc & 1) == 0);
      #pragma unroll
      for (int j = 0; j < 4; ++j) {
        float t  = d[j];
        float pr = __shfl_xor(t, 1);
        float th = 2.f / (1.f + __expf(-2.f * t)) - 1.f;
        float sg = 1.f / (1.f + __expf(-pr));
        sp[mi][j] += even ? (th * sg * wq) : 0.f;
      }
    }
  }
  #pragma unroll
  for (int mi = 0; mi < 2; ++mi) {
    #pragma unroll
    for (int j = 0; j < 4; ++j) {
      float s = sp[mi][j];
      s += __shfl_xor(s, 1); s += __shfl_xor(s, 2);
      s += __shfl_xor(s, 4); s += __shfl_xor(s, 8);
      if ((lane & 15) == 0) {
        int gr = bm0 + wm * 32 + mi * 16 + (lane >> 4) * 4 + j;
        atomicAdd(&scores[gr], s);
      }
    }
  }
}

// ---------------- final: softmax over scores, weighted rowsum ----------------
__global__ __launch_bounds__(1024) void final_kernel(
    const float* __restrict__ scores, const float* __restrict__ rowsum,
    float* __restrict__ out)
{
  __shared__ float red[16], red2[16];
  const int t = threadIdx.x;
  const int lane = t & 63, wid = t >> 6;
  float s[8];
  float m = -3.4e38f;
  #pragma unroll
  for (int i = 0; i < 8; ++i) { s[i] = scores[t + i * 1024]; m = fmaxf(m, s[i]); }
  #pragma unroll
  for (int off = 1; off < 64; off <<= 1) m = fmaxf(m, __shfl_xor(m, off));
  if (lane == 0) red[wid] = m;
  __syncthreads();
  #pragma unroll
  for (int i = 0; i < 16; ++i) m = fmaxf(m, red[i]);
  __syncthreads();

  float se = 0.f, sr = 0.f;
  #pragma unroll
  for (int i = 0; i < 8; ++i) {
    float e = __expf(s[i] - m);
    se += e;
    sr += e * rowsum[t + i * 1024];
  }
  #pragma unroll
  for (int off = 1; off < 64; off <<= 1) { se += __shfl_xor(se, off); sr += __shfl_xor(sr, off); }
  if (lane == 0) { red[wid] = se; red2[wid] = sr; }
  __syncthreads();
  if (t == 0) {
    float tse = 0.f, tsr = 0.f;
    for (int i = 0; i < 16; ++i) { tse += red[i]; tsr += red2[i]; }
    out[0] = tsr / tse;
  }
}

extern "C" void kernel_launch(void* const* d_in, const int* in_sizes, int n_in,
                              void* d_out, int out_size, void* d_ws, size_t ws_size,
                              hipStream_t stream)
{
  const float* x   = (const float*)d_in[0];
  const float* Wm  = (const float*)d_in[1];
  const float* bmv = (const float*)d_in[2];
  const float* u   = (const float*)d_in[3];
  const float* v   = (const float*)d_in[4];
  const float* wv  = (const float*)d_in[5];
  float* out = (float*)d_out;

  if (ws_size < WS_NEED) return;

  char* ws = (char*)d_ws;
  _Float16* xh     = (_Float16*)(ws + OFF_XH);
  _Float16* wh     = (_Float16*)(ws + OFF_WH);
  _Float16* uvh    = (_Float16*)(ws + OFF_UVH);
  _Float16* predsh = (_Float16*)(ws + OFF_PH);
  float*    scores = (float*)(ws + OFF_SC);
  float*    rowsum = (float*)(ws + OFF_RS);

  prep_x_kernel<<<2048, 256, 0, stream>>>(x, xh);
  prep_rest_kernel<<<1288, 256, 0, stream>>>(Wm, u, v, wh, uvh, scores, rowsum);
  gemm1_kernel<<<dim3(32, 8), 512, 0, stream>>>(xh, wh, bmv, out, predsh, rowsum);
  gemm2_kernel<<<dim3(128, 4), 256, 0, stream>>>(predsh, uvh, wv, scores);
  final_kernel<<<1, 1024, 0, stream>>>(scores, rowsum, out + (size_t)B_ * C_);
}

// Round 13
// 90.858 us; speedup vs baseline: 1.0621x; 1.0179x over previous
//
#include <hip/hip_runtime.h>
#include <hip/hip_fp16.h>

typedef _Float16 half8 __attribute__((ext_vector_type(8)));
typedef float f32x4 __attribute__((ext_vector_type(4)));

#define B_   8192
#define DIN  2048
#define C_   1000
#define CP   1024
#define NP2  512   // u,v interleaved rows

// ---- workspace layout (bytes) ----
static const size_t OFF_XH  = 0;                                   // xh  [8192][2048] f16
static const size_t OFF_WH  = OFF_XH  + (size_t)B_ * DIN * 2;      // wh  [1024][2048] f16 (rows>=1000 zero)
static const size_t OFF_UVH = OFF_WH  + (size_t)CP * DIN * 2;      // uvh [512][1024]  f16
static const size_t OFF_PH  = OFF_UVH + (size_t)NP2 * CP * 2;      // predsh [8192][1024] f16
static const size_t OFF_SC  = OFF_PH  + (size_t)B_ * CP * 2;       // scores [8192] f32
static const size_t OFF_RS  = OFF_SC  + (size_t)B_ * 4;            // rowsum [8192] f32
static const size_t WS_NEED = OFF_RS  + (size_t)B_ * 4;

#define FENCE asm volatile("" ::: "memory")
#define BARRIER do { FENCE; __builtin_amdgcn_s_barrier(); FENCE; } while (0)

__device__ __forceinline__ void gload16(const void* g, void* l) {
  __builtin_amdgcn_global_load_lds(
      (const __attribute__((address_space(1))) void*)g,
      (__attribute__((address_space(3))) void*)l, 16, 0, 0);
}

// ---------------- prep: single launch, flat streaming ----------------
// Blocks 0..8191: x(f32)->xh(f16), ONE 8-float group per thread (flat,
// no loop/stride -> max outstanding-miss diversity, canonical ~6TB/s pattern).
// Blocks 8192..9479: Wm/uv conversion + zeroing (exact-sized, r3-validated).
__global__ __launch_bounds__(256) void prep_kernel(
    const float* __restrict__ x, const float* __restrict__ Wm,
    const float* __restrict__ u, const float* __restrict__ v,
    _Float16* __restrict__ xh, _Float16* __restrict__ wh,
    _Float16* __restrict__ uvh, float* __restrict__ scores,
    float* __restrict__ rowsum)
{
  const int b = blockIdx.x;
  if (b < 8192) {
    const long e = ((long)b * 256 + threadIdx.x) * 8;
    float4 p0 = *(const float4*)(x + e);
    float4 p1 = *(const float4*)(x + e + 4);
    half8 h;
    h[0] = (_Float16)p0.x; h[1] = (_Float16)p0.y; h[2] = (_Float16)p0.z; h[3] = (_Float16)p0.w;
    h[4] = (_Float16)p1.x; h[5] = (_Float16)p1.y; h[6] = (_Float16)p1.z; h[7] = (_Float16)p1.w;
    *(half8*)(xh + e) = h;
    return;
  }
  const long NW  = (long)CP * DIN / 8;      //   262,144
  const long NUV = (long)NP2 * CP / 8;      //    65,536
  const long idx = (long)(b - 8192) * 256 + threadIdx.x;   // 0..329,727 exactly
  if (idx < NW) {
    long e = idx * 8;
    int row = (int)(e >> 11);
    half8 h;
    if (row < C_) {
      float4 p0 = *(const float4*)(Wm + e);
      float4 p1 = *(const float4*)(Wm + e + 4);
      h[0] = (_Float16)p0.x; h[1] = (_Float16)p0.y; h[2] = (_Float16)p0.z; h[3] = (_Float16)p0.w;
      h[4] = (_Float16)p1.x; h[5] = (_Float16)p1.y; h[6] = (_Float16)p1.z; h[7] = (_Float16)p1.w;
    } else {
      h = (half8)(_Float16)0.f;
    }
    *(half8*)(wh + e) = h;
  } else if (idx < NW + NUV) {
    long e = (idx - NW) * 8;
    int j = (int)(e >> 10);
    int k = (int)(e & 1023);
    const float* src = (j & 1) ? v : u;
    int p = j >> 1;
    half8 h;
    #pragma unroll
    for (int t = 0; t < 8; ++t) {
      int kk = k + t;
      h[t] = (kk < C_) ? (_Float16)src[(size_t)p * C_ + kk] : (_Float16)0.f;
    }
    *(half8*)(uvh + e) = h;
  } else {
    long e = (idx - NW - NUV) * 8;
    float4 z = {0.f, 0.f, 0.f, 0.f};
    if (e < B_) {
      *(float4*)(scores + e) = z; *(float4*)(scores + e + 4) = z;
    } else {
      long r = e - B_;
      *(float4*)(rowsum + r) = z; *(float4*)(rowsum + r + 4) = z;
    }
  }
}

// ---------------- main GEMM: preds = xh @ wh^T + bm (r5-validated, 45.5us) ----------------
// 256x128 tile, BK=64, 512 threads = 8 waves (4M x 2N), wave tile 64x64.
// 3-buffer LDS (3 x 48KB). 4 phases per K-tile, each phase:
//   {4 ds_read_b128 (for NEXT phase's MFMA) || 1-2 global_load_lds -> barrier
//    -> setprio(1) 8 MFMA setprio(0)}.
// Fragment register reuse: P0 reads A-high(t), P1 reads B-high(t),
// P2 reads A-low(t+1), P3 reads B-low(t+1). vmcnt(4) once per K-tile.
__global__ __launch_bounds__(512) void gemm1_kernel(
    const _Float16* __restrict__ xh, const _Float16* __restrict__ wh,
    const float* __restrict__ bmv, float* __restrict__ preds,
    _Float16* __restrict__ predsh, float* __restrict__ rowsum)
{
  // per buffer: A[256][64] f16 (32KB) @ +0, B[128][64] f16 (16KB) @ +32768
  __shared__ _Float16 lds[3 * 24576];   // 144 KB
  const int tid  = threadIdx.x;
  const int lane = tid & 63;
  const int w    = tid >> 6;       // 0..7
  const int wm   = w >> 1;         // 0..3 (M quarter, 64 rows)
  const int wn   = w & 1;          // 0..1 (N half, 64 cols)
  const int bm0  = blockIdx.x * 256;
  const int bn0  = blockIdx.y * 128;

  f32x4 acc[4][4] = {};

  const _Float16* srcA[4];
  const _Float16* srcB[2];
  #pragma unroll
  for (int k = 0; k < 4; ++k) {
    int slot = k * 512 + tid;
    int row  = slot >> 3;              // 0..255
    int cb   = (slot & 7) << 4;
    int scb  = cb ^ ((row & 7) << 4);
    srcA[k] = xh + (size_t)(bm0 + row) * DIN + (scb >> 1);
  }
  #pragma unroll
  for (int k = 0; k < 2; ++k) {
    int slot = k * 512 + tid;
    int row  = slot >> 3;              // 0..127
    int cb   = (slot & 7) << 4;
    int scb  = cb ^ ((row & 7) << 4);
    srcB[k] = wh + (size_t)(bn0 + row) * DIN + (scb >> 1);
  }

  int aoff[4][2], boff[4][2];
  #pragma unroll
  for (int m = 0; m < 4; ++m) {
    #pragma unroll
    for (int ks = 0; ks < 2; ++ks) {
      int ra = wm * 64 + m * 16 + (lane & 15);
      int kb = ks * 64 + (lane >> 4) * 16;
      aoff[m][ks] = ra * 128 + (kb ^ ((ra & 7) << 4));
    }
  }
  #pragma unroll
  for (int n = 0; n < 4; ++n) {
    #pragma unroll
    for (int ks = 0; ks < 2; ++ks) {
      int rb = wn * 64 + n * 16 + (lane & 15);
      int kb = ks * 64 + (lane >> 4) * 16;
      boff[n][ks] = 32768 + rb * 128 + (kb ^ ((rb & 7) << 4));
    }
  }

  half8 aLa[2][2], aLb[2][2], aHf[2][2], bLf[2][2], bHf[2][2];

  auto stA = [&](int cs, int k) {
    gload16(srcA[k], (char*)lds + cs * 49152 + k * 8192 + w * 1024);
  };
  auto stB = [&](int cs, int k) {
    gload16(srcB[k], (char*)lds + cs * 49152 + 32768 + k * 8192 + w * 1024);
  };
  auto advance = [&]() {
    #pragma unroll
    for (int k = 0; k < 4; ++k) srcA[k] += 64;
    srcB[0] += 64; srcB[1] += 64;
  };
  auto rdAH = [&](const char* b) {
    #pragma unroll
    for (int m = 0; m < 2; ++m)
      #pragma unroll
      for (int ks = 0; ks < 2; ++ks)
        aHf[m][ks] = *(const half8*)(b + aoff[m + 2][ks]);
  };
  auto rdBH = [&](const char* b) {
    #pragma unroll
    for (int n = 0; n < 2; ++n)
      #pragma unroll
      for (int ks = 0; ks < 2; ++ks)
        bHf[n][ks] = *(const half8*)(b + boff[n + 2][ks]);
  };
  auto rdAL = [&](const char* b, half8 (&d)[2][2]) {
    #pragma unroll
    for (int m = 0; m < 2; ++m)
      #pragma unroll
      for (int ks = 0; ks < 2; ++ks)
        d[m][ks] = *(const half8*)(b + aoff[m][ks]);
  };
  auto rdBL = [&](const char* b) {
    #pragma unroll
    for (int n = 0; n < 2; ++n)
      #pragma unroll
      for (int ks = 0; ks < 2; ++ks)
        bLf[n][ks] = *(const half8*)(b + boff[n][ks]);
  };
  auto mfLL = [&](half8 (&aL)[2][2]) {
    #pragma unroll
    for (int m = 0; m < 2; ++m)
      #pragma unroll
      for (int n = 0; n < 2; ++n)
        #pragma unroll
        for (int ks = 0; ks < 2; ++ks)
          acc[m][n] = __builtin_amdgcn_mfma_f32_16x16x32_f16(aL[m][ks], bLf[n][ks], acc[m][n], 0, 0, 0);
  };
  auto mfHL = [&]() {
    #pragma unroll
    for (int m = 0; m < 2; ++m)
      #pragma unroll
      for (int n = 0; n < 2; ++n)
        #pragma unroll
        for (int ks = 0; ks < 2; ++ks)
          acc[m + 2][n] = __builtin_amdgcn_mfma_f32_16x16x32_f16(aHf[m][ks], bLf[n][ks], acc[m + 2][n], 0, 0, 0);
  };
  auto mfLH = [&](half8 (&aL)[2][2]) {
    #pragma unroll
    for (int m = 0; m < 2; ++m)
      #pragma unroll
      for (int n = 0; n < 2; ++n)
        #pragma unroll
        for (int ks = 0; ks < 2; ++ks)
          acc[m][n + 2] = __builtin_amdgcn_mfma_f32_16x16x32_f16(aL[m][ks], bHf[n][ks], acc[m][n + 2], 0, 0, 0);
  };
  auto mfHH = [&]() {
    #pragma unroll
    for (int m = 0; m < 2; ++m)
      #pragma unroll
      for (int n = 0; n < 2; ++n)
        #pragma unroll
        for (int ks = 0; ks < 2; ++ks)
          acc[m + 2][n + 2] = __builtin_amdgcn_mfma_f32_16x16x32_f16(aHf[m][ks], bHf[n][ks], acc[m + 2][n + 2], 0, 0, 0);
  };

  // ---- prologue: stage tile0 -> buf0, tile1 -> buf1 ----
  #pragma unroll
  for (int k = 0; k < 4; ++k) stA(0, k);
  stB(0, 0); stB(0, 1);
  advance();
  #pragma unroll
  for (int k = 0; k < 4; ++k) stA(1, k);
  stB(1, 0); stB(1, 1);
  advance();
  asm volatile("s_waitcnt vmcnt(6)" ::: "memory");   // tile0 resident
  BARRIER;
  rdAL((const char*)lds, aLa);
  rdBL((const char*)lds);

  // ---- main loop: tiles 0..29, two per iteration ----
  int c0 = 0;
  #pragma unroll 1
  for (int t = 0; t < 30; t += 2) {
    const int c1 = (c0 == 2) ? 0 : c0 + 1;
    const int c2 = (c1 == 2) ? 0 : c1 + 1;
    const char* bt  = (const char*)lds + c0 * 49152;
    const char* bn1 = (const char*)lds + c1 * 49152;
    const char* bn2 = (const char*)lds + c2 * 49152;

    // ===== even tile t (current A-low = aLa) =====
    rdAH(bt);  stA(c2, 0); stA(c2, 1);                 // P0
    BARRIER;
    __builtin_amdgcn_s_setprio(1); mfLL(aLa); __builtin_amdgcn_s_setprio(0);

    rdBH(bt);  stA(c2, 2); stA(c2, 3);                 // P1
    asm volatile("s_waitcnt vmcnt(4)" ::: "memory");   // tile t+1 resident
    BARRIER;
    __builtin_amdgcn_s_setprio(1); mfHL(); __builtin_amdgcn_s_setprio(0);

    rdAL(bn1, aLb);  stB(c2, 0);                       // P2 (prefetch t+1 A-low)
    BARRIER;
    __builtin_amdgcn_s_setprio(1); mfLH(aLa); __builtin_amdgcn_s_setprio(0);

    rdBL(bn1);  stB(c2, 1); advance();                 // P3 (prefetch t+1 B-low)
    BARRIER;
    __builtin_amdgcn_s_setprio(1); mfHH(); __builtin_amdgcn_s_setprio(0);

    // ===== odd tile t+1 (current A-low = aLb) =====
    rdAH(bn1);  stA(c0, 0); stA(c0, 1);                // stage tile t+3 -> buf c0
    BARRIER;
    __builtin_amdgcn_s_setprio(1); mfLL(aLb); __builtin_amdgcn_s_setprio(0);

    rdBH(bn1);  stA(c0, 2); stA(c0, 3);
    asm volatile("s_waitcnt vmcnt(4)" ::: "memory");   // tile t+2 resident
    BARRIER;
    __builtin_amdgcn_s_setprio(1); mfHL(); __builtin_amdgcn_s_setprio(0);

    rdAL(bn2, aLa);  stB(c0, 0);                       // prefetch t+2 A-low
    BARRIER;
    __builtin_amdgcn_s_setprio(1); mfLH(aLb); __builtin_amdgcn_s_setprio(0);

    rdBL(bn2);  stB(c0, 1); advance();                 // prefetch t+2 B-low
    BARRIER;
    __builtin_amdgcn_s_setprio(1); mfHH(); __builtin_amdgcn_s_setprio(0);

    c0 = c2;
  }

  // ---- tail: tile 30 (buf0, cur aLa; prefetch tile31 from buf1) ----
  {
    const char* bt  = (const char*)lds;
    const char* bn1 = (const char*)lds + 49152;
    rdAH(bt);
    BARRIER;
    __builtin_amdgcn_s_setprio(1); mfLL(aLa); __builtin_amdgcn_s_setprio(0);
    rdBH(bt);
    asm volatile("s_waitcnt vmcnt(0)" ::: "memory");   // tile31 resident
    BARRIER;
    __builtin_amdgcn_s_setprio(1); mfHL(); __builtin_amdgcn_s_setprio(0);
    rdAL(bn1, aLb);
    BARRIER;
    __builtin_amdgcn_s_setprio(1); mfLH(aLa); __builtin_amdgcn_s_setprio(0);
    rdBL(bn1);
    BARRIER;
    __builtin_amdgcn_s_setprio(1); mfHH(); __builtin_amdgcn_s_setprio(0);
    // ---- tile 31 (buf1, cur aLb): no barriers needed ----
    rdAH(bn1); rdBH(bn1);
    mfLL(aLb); mfHL(); mfLH(aLb); mfHH();
  }

  // ---- epilogue: bias add, f32 preds, f16 predsh, rowsum partials ----
  float rp[4][4] = {};
  #pragma unroll
  for (int m = 0; m < 4; ++m) {
    #pragma unroll
    for (int n = 0; n < 4; ++n) {
      f32x4 d = acc[m][n];
      int gc = bn0 + wn * 64 + n * 16 + (lane & 15);
      float bias = (gc < C_) ? bmv[gc] : 0.f;
      #pragma unroll
      for (int j = 0; j < 4; ++j) {
        int gr = bm0 + wm * 64 + m * 16 + (lane >> 4) * 4 + j;
        float val = d[j] + bias;
        predsh[(size_t)gr * CP + gc] = (_Float16)val;
        if (gc < C_) preds[(size_t)gr * C_ + gc] = val;
        rp[m][j] += val;
      }
    }
  }
  #pragma unroll
  for (int m = 0; m < 4; ++m) {
    #pragma unroll
    for (int j = 0; j < 4; ++j) {
      float s = rp[m][j];
      s += __shfl_xor(s, 1); s += __shfl_xor(s, 2);
      s += __shfl_xor(s, 4); s += __shfl_xor(s, 8);
      if ((lane & 15) == 0) {
        int gr = bm0 + wm * 64 + m * 16 + (lane >> 4) * 4 + j;
        atomicAdd(&rowsum[gr], s);
      }
    }
  }
}

// ---------------- gating GEMM: scores partials (r5-validated) ----------------
__global__ __launch_bounds__(256) void gemm2_kernel(
    const _Float16* __restrict__ predsh, const _Float16* __restrict__ uvh,
    const float* __restrict__ wv, float* __restrict__ scores)
{
  __shared__ _Float16 sA[2][64 * 64];
  __shared__ _Float16 sB[2][128 * 64];
  const int tid  = threadIdx.x;
  const int lane = tid & 63;
  const int w    = tid >> 6;
  const int wm   = w >> 1, wn = w & 1;   // wave owns 32x64
  const int bm0  = blockIdx.x * 64;
  const int bn0  = blockIdx.y * 128;

  f32x4 acc[2][4] = {};

  const _Float16* srcA[2]; const _Float16* srcB[4];
  #pragma unroll
  for (int i = 0; i < 2; ++i) {
    int slot = i * 256 + tid;
    int row  = slot >> 3;
    int cb   = (slot & 7) << 4;
    int scb  = cb ^ ((row & 7) << 4);
    srcA[i] = predsh + (size_t)(bm0 + row) * CP + (scb >> 1);
  }
  #pragma unroll
  for (int i = 0; i < 4; ++i) {
    int slot = i * 256 + tid;
    int row  = slot >> 3;
    int cb   = (slot & 7) << 4;
    int scb  = cb ^ ((row & 7) << 4);
    srcB[i] = uvh + (size_t)(bn0 + row) * CP + (scb >> 1);
  }
  int aoff[2][2], boff[4][2];
  #pragma unroll
  for (int ks = 0; ks < 2; ++ks) {
    int kb = ks * 64 + (lane >> 4) * 16;
    #pragma unroll
    for (int mi = 0; mi < 2; ++mi) {
      int ra = wm * 32 + mi * 16 + (lane & 15);
      aoff[mi][ks] = ra * 128 + (kb ^ ((ra & 7) << 4));
    }
    #pragma unroll
    for (int ni = 0; ni < 4; ++ni) {
      int rb = wn * 64 + ni * 16 + (lane & 15);
      boff[ni][ks] = rb * 128 + (kb ^ ((rb & 7) << 4));
    }
  }

  auto stage = [&](int c) {
    #pragma unroll
    for (int i = 0; i < 2; ++i) {
      gload16(srcA[i], &sA[c][(i * 4 + w) * 512]);
      srcA[i] += 64;
    }
    #pragma unroll
    for (int i = 0; i < 4; ++i) {
      gload16(srcB[i], &sB[c][(i * 4 + w) * 512]);
      srcB[i] += 64;
    }
  };

  auto compute = [&](int c) {
    const char* bA = (const char*)&sA[c][0];
    const char* bB = (const char*)&sB[c][0];
    #pragma unroll
    for (int ks = 0; ks < 2; ++ks) {
      half8 a[2], b[4];
      #pragma unroll
      for (int mi = 0; mi < 2; ++mi) a[mi] = *(const half8*)(bA + aoff[mi][ks]);
      #pragma unroll
      for (int ni = 0; ni < 4; ++ni) b[ni] = *(const half8*)(bB + boff[ni][ks]);
      #pragma unroll
      for (int mi = 0; mi < 2; ++mi)
        #pragma unroll
        for (int ni = 0; ni < 4; ++ni)
          acc[mi][ni] = __builtin_amdgcn_mfma_f32_16x16x32_f16(a[mi], b[ni], acc[mi][ni], 0, 0, 0);
    }
  };

  const int NT = CP / 64;   // 16
  stage(0);
  #pragma unroll 1
  for (int kt = 0; kt < NT; kt += 2) {
    stage(1);
    asm volatile("s_waitcnt vmcnt(6)" ::: "memory");
    BARRIER;
    compute(0);
    BARRIER;
    if (kt + 2 < NT) {
      stage(0);
      asm volatile("s_waitcnt vmcnt(6)" ::: "memory");
    } else {
      asm volatile("s_waitcnt vmcnt(0)" ::: "memory");
    }
    BARRIER;
    compute(1);
    BARRIER;
  }

  float sp[2][4] = {};
  #pragma unroll
  for (int mi = 0; mi < 2; ++mi) {
    #pragma unroll
    for (int ni = 0; ni < 4; ++ni) {
      f32x4 d = acc[mi][ni];
      int gc = bn0 + wn * 64 + ni * 16 + (lane & 15);   // even=u col, odd=v col
      float wq = wv[gc >> 1];
      bool even = ((gc & 1) == 0);
      #pragma unroll
      for (int j = 0; j < 4; ++j) {
        float t  = d[j];
        float pr = __shfl_xor(t, 1);
        float th = 2.f / (1.f + __expf(-2.f * t)) - 1.f;
        float sg = 1.f / (1.f + __expf(-pr));
        sp[mi][j] += even ? (th * sg * wq) : 0.f;
      }
    }
  }
  #pragma unroll
  for (int mi = 0; mi < 2; ++mi) {
    #pragma unroll
    for (int j = 0; j < 4; ++j) {
      float s = sp[mi][j];
      s += __shfl_xor(s, 1); s += __shfl_xor(s, 2);
      s += __shfl_xor(s, 4); s += __shfl_xor(s, 8);
      if ((lane & 15) == 0) {
        int gr = bm0 + wm * 32 + mi * 16 + (lane >> 4) * 4 + j;
        atomicAdd(&scores[gr], s);
      }
    }
  }
}

// ---------------- final: softmax over scores, weighted rowsum ----------------
__global__ __launch_bounds__(1024) void final_kernel(
    const float* __restrict__ scores, const float* __restrict__ rowsum,
    float* __restrict__ out)
{
  __shared__ float red[16], red2[16];
  const int t = threadIdx.x;
  const int lane = t & 63, wid = t >> 6;
  float s[8];
  float m = -3.4e38f;
  #pragma unroll
  for (int i = 0; i < 8; ++i) { s[i] = scores[t + i * 1024]; m = fmaxf(m, s[i]); }
  #pragma unroll
  for (int off = 1; off < 64; off <<= 1) m = fmaxf(m, __shfl_xor(m, off));
  if (lane == 0) red[wid] = m;
  __syncthreads();
  #pragma unroll
  for (int i = 0; i < 16; ++i) m = fmaxf(m, red[i]);
  __syncthreads();

  float se = 0.f, sr = 0.f;
  #pragma unroll
  for (int i = 0; i < 8; ++i) {
    float e = __expf(s[i] - m);
    se += e;
    sr += e * rowsum[t + i * 1024];
  }
  #pragma unroll
  for (int off = 1; off < 64; off <<= 1) { se += __shfl_xor(se, off); sr += __shfl_xor(sr, off); }
  if (lane == 0) { red[wid] = se; red2[wid] = sr; }
  __syncthreads();
  if (t == 0) {
    float tse = 0.f, tsr = 0.f;
    for (int i = 0; i < 16; ++i) { tse += red[i]; tsr += red2[i]; }
    out[0] = tsr / tse;
  }
}

extern "C" void kernel_launch(void* const* d_in, const int* in_sizes, int n_in,
                              void* d_out, int out_size, void* d_ws, size_t ws_size,
                              hipStream_t stream)
{
  const float* x   = (const float*)d_in[0];
  const float* Wm  = (const float*)d_in[1];
  const float* bmv = (const float*)d_in[2];
  const float* u   = (const float*)d_in[3];
  const float* v   = (const float*)d_in[4];
  const float* wv  = (const float*)d_in[5];
  float* out = (float*)d_out;

  if (ws_size < WS_NEED) return;

  char* ws = (char*)d_ws;
  _Float16* xh     = (_Float16*)(ws + OFF_XH);
  _Float16* wh     = (_Float16*)(ws + OFF_WH);
  _Float16* uvh    = (_Float16*)(ws + OFF_UVH);
  _Float16* predsh = (_Float16*)(ws + OFF_PH);
  float*    scores = (float*)(ws + OFF_SC);
  float*    rowsum = (float*)(ws + OFF_RS);

  prep_kernel<<<9480, 256, 0, stream>>>(x, Wm, u, v, xh, wh, uvh, scores, rowsum);
  gemm1_kernel<<<dim3(32, 8), 512, 0, stream>>>(xh, wh, bmv, out, predsh, rowsum);
  gemm2_kernel<<<dim3(128, 4), 256, 0, stream>>>(predsh, uvh, wv, scores);
  final_kernel<<<1, 1024, 0, stream>>>(scores, rowsum, out + (size_t)B_ * C_);
}